// Round 4
// baseline (1138.076 us; speedup 1.0000x reference)
//
#include <hip/hip_runtime.h>
#include <hip/hip_fp16.h>
#include <math.h>

// DecoderRNN: output depends ONLY on batch row 0 (reference broadcasts
// totoken_w[idx][0] over the batch). Row-0 trajectory via GEMVs.
// This round: fp16 weight compression (one-time convert) + fused
// fc_argmax+finalize (atomic last-block pattern).
//
// Dims: H=1024, V=32000, E=18432, B=256, T=15.

#define HDIM 1024
#define VDIM 32000
#define EDIM 18432
#define BDIM 256
#define TSTEPS 15
#define FC_BLOCKS 512

__device__ inline float wave_sum(float v) {
#pragma unroll
  for (int off = 32; off; off >>= 1) v += __shfl_down(v, off, 64);
  return v;
}

template <int NT>
__device__ inline float block_allreduce_sum(float v, float* sm) {
  const int NW = NT / 64;
  int lane = threadIdx.x & 63, wave = threadIdx.x >> 6;
  v = wave_sum(v);
  if (lane == 0) sm[wave] = v;
  __syncthreads();
  float r = (threadIdx.x < NW) ? sm[threadIdx.x] : 0.f;
  if (wave == 0) {
    r = wave_sum(r);
    if (lane == 0) sm[0] = r;
  }
  __syncthreads();
  r = sm[0];
  __syncthreads();  // safe for helper reuse
  return r;
}

// ---- fp32 -> fp16 bulk convert: 8 elems/thread/iter (float4 in, half8 out).
__global__ __launch_bounds__(256) void f2h8(const float* __restrict__ src,
                                            __half* __restrict__ dst, int n8) {
  int i = blockIdx.x * 256 + threadIdx.x;
  int stride = gridDim.x * 256;
  const float4* s = (const float4*)src;
  for (; i < n8; i += stride) {
    float4 a = s[2 * i], b = s[2 * i + 1];
    __half2 hh[4];
    hh[0] = __floats2half2_rn(a.x, a.y);
    hh[1] = __floats2half2_rn(a.z, a.w);
    hh[2] = __floats2half2_rn(b.x, b.y);
    hh[3] = __floats2half2_rn(b.z, b.w);
    ((float4*)dst)[i] = *(float4*)hh;
  }
}

__global__ void zero_counters(int* c) {
  if (threadIdx.x < 32) c[threadIdx.x] = 0;
}

// y[r] = relu(dot(W[r,:], x) + b[r]); one block per row. fp32 (init only).
__global__ __launch_bounds__(256) void gemv_relu(
    const float* __restrict__ W, const float* __restrict__ x,
    const float* __restrict__ b, float* __restrict__ y, int K) {
  __shared__ float sm[4];
  int r = blockIdx.x;
  const float4* wr = (const float4*)(W + (size_t)r * K);
  const float4* xv = (const float4*)x;
  int nk = K >> 2;
  float s = 0.f;
  for (int k = threadIdx.x; k < nk; k += 256) {
    float4 a = wr[k], c = xv[k];
    s = fmaf(a.x, c.x, fmaf(a.y, c.y, fmaf(a.z, c.z, fmaf(a.w, c.w, s))));
  }
  s = block_allreduce_sum<256>(s, sm);
  if (threadIdx.x == 0) y[r] = fmaxf(s + b[r], 0.f);
}

// h = LN(preh)*gh+bh ; c = LN(prec)*gc+bc. Single block, 1024 threads.
__global__ __launch_bounds__(1024) void ln2_kernel(
    const float* __restrict__ ph, const float* __restrict__ pc,
    const float* __restrict__ gh, const float* __restrict__ bh,
    const float* __restrict__ gc, const float* __restrict__ bc,
    float* __restrict__ h, float* __restrict__ c) {
  __shared__ float sm[16];
  int t = threadIdx.x;
  float xh = ph[t];
  float m = block_allreduce_sum<1024>(xh, sm) * (1.f / 1024.f);
  float d = xh - m;
  float var = block_allreduce_sum<1024>(d * d, sm) * (1.f / 1024.f);
  h[t] = d / sqrtf(var + 1e-5f) * gh[t] + bh[t];
  float xc = pc[t];
  float mc = block_allreduce_sum<1024>(xc, sm) * (1.f / 1024.f);
  float dc = xc - mc;
  float vc = block_allreduce_sum<1024>(dc * dc, sm) * (1.f / 1024.f);
  c[t] = dc / sqrtf(vc + 1e-5f) * gc[t] + bc[t];
}

// One block per hidden unit j; wave w computes gate w. fp16 weights, fp32 x/h.
__global__ __launch_bounds__(256) void lstm_cell_h(
    const float* __restrict__ x, const float* __restrict__ hs,
    const float* __restrict__ cs, const __half* __restrict__ Wih,
    const __half* __restrict__ Whh, const float* __restrict__ bih,
    const float* __restrict__ bhh, float* __restrict__ hout,
    float* __restrict__ cout) {
  __shared__ float g[4];
  int j = blockIdx.x;
  int lane = threadIdx.x & 63, wave = threadIdx.x >> 6;
  size_t row = (size_t)(j + wave * HDIM);
  const float4* wi = (const float4*)(Wih + row * HDIM);  // 128 x (8 halves)
  const float4* wh = (const float4*)(Whh + row * HDIM);
  const float4* xv = (const float4*)x;
  const float4* hv = (const float4*)hs;
  float s = 0.f;
#pragma unroll
  for (int it = 0; it < 2; ++it) {
    int k = lane + (it << 6);
    float4 wa = wi[k], wb = wh[k];
    float4 x0 = xv[2 * k], x1 = xv[2 * k + 1];
    float4 h0 = hv[2 * k], h1 = hv[2 * k + 1];
    const __half2* A = (const __half2*)&wa;
    const __half2* B = (const __half2*)&wb;
    float2 f;
    f = __half22float2(A[0]); s = fmaf(f.x, x0.x, fmaf(f.y, x0.y, s));
    f = __half22float2(A[1]); s = fmaf(f.x, x0.z, fmaf(f.y, x0.w, s));
    f = __half22float2(A[2]); s = fmaf(f.x, x1.x, fmaf(f.y, x1.y, s));
    f = __half22float2(A[3]); s = fmaf(f.x, x1.z, fmaf(f.y, x1.w, s));
    f = __half22float2(B[0]); s = fmaf(f.x, h0.x, fmaf(f.y, h0.y, s));
    f = __half22float2(B[1]); s = fmaf(f.x, h0.z, fmaf(f.y, h0.w, s));
    f = __half22float2(B[2]); s = fmaf(f.x, h1.x, fmaf(f.y, h1.y, s));
    f = __half22float2(B[3]); s = fmaf(f.x, h1.z, fmaf(f.y, h1.w, s));
  }
  s = wave_sum(s);
  if (lane == 0) g[wave] = s + bih[row] + bhh[row];
  __syncthreads();
  if (threadIdx.x == 0) {
    float gi = g[0], gf = g[1], gg = g[2], go = g[3];
    float si = 1.f / (1.f + expf(-gi));
    float sf = 1.f / (1.f + expf(-gf));
    float so = 1.f / (1.f + expf(-go));
    float cn = sf * cs[j] + si * tanhf(gg);
    cout[j] = cn;
    hout[j] = so * tanhf(cn);
  }
}

// fc GEMV + per-block argmax partial + last-block finalize (atomic ticket).
// Finalize: global argmax, out column, word gather, x1h=LN(h1)+h0, x1c=LN(c1)+c0.
__global__ __launch_bounds__(256) void fc_argmax_fin(
    const __half* __restrict__ W, const float* __restrict__ b,
    const float* __restrict__ x, float* __restrict__ bmax,
    int* __restrict__ bidx, int* __restrict__ counter,
    const float* __restrict__ totoken, const float* __restrict__ embed,
    const float* __restrict__ h1, const float* __restrict__ c1,
    const float* __restrict__ h0v, const float* __restrict__ c0v,
    const float* __restrict__ gh, const float* __restrict__ bh,
    const float* __restrict__ gc, const float* __restrict__ bc,
    float* __restrict__ word, float* __restrict__ x1h, float* __restrict__ x1c,
    float* __restrict__ out, int step) {
  __shared__ float sv[4];
  __shared__ int sidx[4];
  __shared__ int s_last;
  __shared__ int s_idx;
  int t = threadIdx.x, lane = t & 63, wave = t >> 6;
  int wid = blockIdx.x * 4 + wave;
  const float4* xv = (const float4*)x;
  float best = -3.4e38f;
  int bi = 0x7fffffff;
  for (int row = wid; row < VDIM; row += FC_BLOCKS * 4) {
    const float4* wr = (const float4*)(W + (size_t)row * HDIM);
    float s = 0.f;
#pragma unroll
    for (int it = 0; it < 2; ++it) {
      int k = lane + (it << 6);
      float4 wa = wr[k];
      float4 x0 = xv[2 * k], x1 = xv[2 * k + 1];
      const __half2* A = (const __half2*)&wa;
      float2 f;
      f = __half22float2(A[0]); s = fmaf(f.x, x0.x, fmaf(f.y, x0.y, s));
      f = __half22float2(A[1]); s = fmaf(f.x, x0.z, fmaf(f.y, x0.w, s));
      f = __half22float2(A[2]); s = fmaf(f.x, x1.x, fmaf(f.y, x1.y, s));
      f = __half22float2(A[3]); s = fmaf(f.x, x1.z, fmaf(f.y, x1.w, s));
    }
    s = wave_sum(s);
    if (lane == 0) {
      s += b[row];
      if (s > best) { best = s; bi = row; }  // ascending rows -> first-max kept
    }
  }
  if (lane == 0) { sv[wave] = best; sidx[wave] = bi; }
  __syncthreads();
  if (t == 0) {
    float v = sv[0];
    int ix = sidx[0];
#pragma unroll
    for (int w2 = 1; w2 < 4; ++w2) {
      if (sv[w2] > v || (sv[w2] == v && sidx[w2] < ix)) { v = sv[w2]; ix = sidx[w2]; }
    }
    bmax[blockIdx.x] = v;
    bidx[blockIdx.x] = ix;
    __threadfence();  // publish partial before ticket
    int old = atomicAdd(counter, 1);
    s_last = (old == FC_BLOCKS - 1) ? 1 : 0;
  }
  __syncthreads();
  if (!s_last) return;
  // ---- last block: finalize with 256 threads ----
  __threadfence();  // acquire: see all partials
  float v0 = bmax[t];       int i0 = bidx[t];
  float v1 = bmax[t + 256]; int i1 = bidx[t + 256];
  if (v1 > v0 || (v1 == v0 && i1 < i0)) { v0 = v1; i0 = i1; }
#pragma unroll
  for (int off = 32; off; off >>= 1) {
    float ov = __shfl_down(v0, off, 64);
    int oi = __shfl_down(i0, off, 64);
    if (ov > v0 || (ov == v0 && oi < i0)) { v0 = ov; i0 = oi; }
  }
  if (lane == 0) { sv[wave] = v0; sidx[wave] = i0; }
  __syncthreads();
  if (t == 0) {
    float bv = sv[0];
    int bix = sidx[0];
#pragma unroll
    for (int w2 = 1; w2 < 4; ++w2) {
      if (sv[w2] > bv || (sv[w2] == bv && sidx[w2] < bix)) { bv = sv[w2]; bix = sidx[w2]; }
    }
    s_idx = bix;
  }
  __syncthreads();
  int idx = s_idx;
  float tv = totoken[idx];
  out[t * TSTEPS + step] = tv;  // 256 rows, column `step`
  for (int k = t; k < HDIM; k += 256) word[k] = embed[(size_t)idx * HDIM + k];
  __syncthreads();  // sv about to be reused by allreduce
  // x1h = LN(h1)*gh+bh + h0 (4 elems/thread)
  float a0 = h1[t], a1 = h1[t + 256], a2 = h1[t + 512], a3 = h1[t + 768];
  float m = block_allreduce_sum<256>(a0 + a1 + a2 + a3, sv) * (1.f / 1024.f);
  float d0 = a0 - m, d1 = a1 - m, d2 = a2 - m, d3 = a3 - m;
  float var = block_allreduce_sum<256>(d0 * d0 + d1 * d1 + d2 * d2 + d3 * d3, sv) *
              (1.f / 1024.f);
  float inv = 1.f / sqrtf(var + 1e-5f);
  x1h[t]       = d0 * inv * gh[t]       + bh[t]       + h0v[t];
  x1h[t + 256] = d1 * inv * gh[t + 256] + bh[t + 256] + h0v[t + 256];
  x1h[t + 512] = d2 * inv * gh[t + 512] + bh[t + 512] + h0v[t + 512];
  x1h[t + 768] = d3 * inv * gh[t + 768] + bh[t + 768] + h0v[t + 768];
  // x1c = LN(c1)*gc+bc + c0
  float b0 = c1[t], b1 = c1[t + 256], b2 = c1[t + 512], b3 = c1[t + 768];
  float mc = block_allreduce_sum<256>(b0 + b1 + b2 + b3, sv) * (1.f / 1024.f);
  float e0 = b0 - mc, e1 = b1 - mc, e2 = b2 - mc, e3 = b3 - mc;
  float vc = block_allreduce_sum<256>(e0 * e0 + e1 * e1 + e2 * e2 + e3 * e3, sv) *
             (1.f / 1024.f);
  float invc = 1.f / sqrtf(vc + 1e-5f);
  x1c[t]       = e0 * invc * gc[t]       + bc[t]       + c0v[t];
  x1c[t + 256] = e1 * invc * gc[t + 256] + bc[t + 256] + c0v[t + 256];
  x1c[t + 512] = e2 * invc * gc[t + 512] + bc[t + 512] + c0v[t + 512];
  x1c[t + 768] = e3 * invc * gc[t + 768] + bc[t + 768] + c0v[t + 768];
}

extern "C" void kernel_launch(void* const* d_in, const int* in_sizes, int n_in,
                              void* d_out, int out_size, void* d_ws,
                              size_t ws_size, hipStream_t stream) {
  (void)in_sizes; (void)n_in; (void)out_size; (void)ws_size;
  const float* features = (const float*)d_in[0];
  const float* fc1_w    = (const float*)d_in[1];
  const float* fc1_b    = (const float*)d_in[2];
  const float* init_h_w = (const float*)d_in[3];
  const float* init_h_b = (const float*)d_in[4];
  const float* init_c_w = (const float*)d_in[5];
  const float* init_c_b = (const float*)d_in[6];
  const float* ln_h_g   = (const float*)d_in[7];
  const float* ln_h_b   = (const float*)d_in[8];
  const float* ln_c_g   = (const float*)d_in[9];
  const float* ln_c_b   = (const float*)d_in[10];
  const float* w_ih1    = (const float*)d_in[11];
  const float* w_hh1    = (const float*)d_in[12];
  const float* b_ih1    = (const float*)d_in[13];
  const float* b_hh1    = (const float*)d_in[14];
  const float* w_ih2    = (const float*)d_in[15];
  const float* w_hh2    = (const float*)d_in[16];
  const float* b_ih2    = (const float*)d_in[17];
  const float* b_hh2    = (const float*)d_in[18];
  const float* fc_w     = (const float*)d_in[19];
  const float* fc_b     = (const float*)d_in[20];
  const float* embed_w  = (const float*)d_in[21];
  const float* totoken  = (const float*)d_in[22];
  // d_in[23] = max_length (15), hard-coded as TSTEPS.

  float* ws = (float*)d_ws;
  float* feat = ws + 0;
  float* preh = ws + 1024;
  float* prec = ws + 2048;
  float* h0   = ws + 3072;
  float* c0   = ws + 4096;
  float* h1   = ws + 5120;
  float* c1   = ws + 6144;
  float* h2b[2] = {ws + 7168, ws + 8192};
  float* c2b[2] = {ws + 9216, ws + 10240};
  float* h3b[2] = {ws + 11264, ws + 12288};
  float* c3b[2] = {ws + 13312, ws + 14336};
  float* x1h  = ws + 15360;
  float* x1c  = ws + 16384;
  float* word = ws + 17408;
  float* bmax = ws + 18432;                 // 512 floats
  int*   bidx = (int*)(ws + 18944);         // 512 ints
  int*   counters = (int*)(ws + 19456);     // 32 ints
  float* out  = (float*)d_out;

  // fp16 weight pool starts at 128 KB into ws (~101 MB total).
  __half* hb   = (__half*)((char*)d_ws + (1 << 17));
  __half* fc_h = hb;                              // 32000*1024 halves
  __half* w1i_h = hb + (size_t)32768 * 1024;      // padded start
  __half* w1h_h = w1i_h + (size_t)4 * 1024 * 1024;
  __half* w2i_h = w1h_h + (size_t)4 * 1024 * 1024;
  __half* w2h_h = w2i_h + (size_t)4 * 1024 * 1024;

  // one-time per call: counters + fp16 conversion
  zero_counters<<<1, 64, 0, stream>>>(counters);
  f2h8<<<2048, 256, 0, stream>>>(fc_w,  fc_h,  (VDIM * HDIM) / 8);
  f2h8<<<512, 256, 0, stream>>>(w_ih1, w1i_h, (4 * HDIM * HDIM) / 8);
  f2h8<<<512, 256, 0, stream>>>(w_hh1, w1h_h, (4 * HDIM * HDIM) / 8);
  f2h8<<<512, 256, 0, stream>>>(w_ih2, w2i_h, (4 * HDIM * HDIM) / 8);
  f2h8<<<512, 256, 0, stream>>>(w_hh2, w2h_h, (4 * HDIM * HDIM) / 8);

  // init chain (fp32)
  gemv_relu<<<HDIM, 256, 0, stream>>>(fc1_w, features, fc1_b, feat, EDIM);
  gemv_relu<<<HDIM, 256, 0, stream>>>(init_h_w, feat, init_h_b, preh, HDIM);
  gemv_relu<<<HDIM, 256, 0, stream>>>(init_c_w, feat, init_c_b, prec, HDIM);
  ln2_kernel<<<1, 1024, 0, stream>>>(preh, prec, ln_h_g, ln_h_b, ln_c_g, ln_c_b,
                                     h0, c0);
  // step 0
  lstm_cell_h<<<HDIM, 256, 0, stream>>>(feat, h0, c0, w1i_h, w1h_h, b_ih1,
                                        b_hh1, h1, c1);
  lstm_cell_h<<<HDIM, 256, 0, stream>>>(h1, h0, c0, w2i_h, w2h_h, b_ih2, b_hh2,
                                        h2b[0], c2b[0]);
  lstm_cell_h<<<HDIM, 256, 0, stream>>>(h2b[0], h0, c0, w2i_h, w2h_h, b_ih2,
                                        b_hh2, h3b[0], c3b[0]);
  fc_argmax_fin<<<FC_BLOCKS, 256, 0, stream>>>(
      fc_h, fc_b, h3b[0], bmax, bidx, counters + 0, totoken, embed_w, h1, c1,
      h0, c0, ln_h_g, ln_h_b, ln_c_g, ln_c_b, word, x1h, x1c, out, 0);
  int cur = 0;
  for (int t = 1; t < TSTEPS; ++t) {
    int nxt = cur ^ 1;
    lstm_cell_h<<<HDIM, 256, 0, stream>>>(word, x1h, x1c, w1i_h, w1h_h, b_ih1,
                                          b_hh1, h1, c1);
    lstm_cell_h<<<HDIM, 256, 0, stream>>>(h1, h2b[cur], c2b[cur], w2i_h, w2h_h,
                                          b_ih2, b_hh2, h2b[nxt], c2b[nxt]);
    lstm_cell_h<<<HDIM, 256, 0, stream>>>(h2b[nxt], h3b[cur], c3b[cur], w2i_h,
                                          w2h_h, b_ih2, b_hh2, h3b[nxt],
                                          c3b[nxt]);
    fc_argmax_fin<<<FC_BLOCKS, 256, 0, stream>>>(
        fc_h, fc_b, h3b[nxt], bmax, bidx, counters + t, totoken, embed_w, h1,
        c1, h0, c0, ln_h_g, ln_h_b, ln_c_g, ln_c_b, word, x1h, x1c, out, t);
    cur = nxt;
  }
}